// Round 8
// baseline (388.129 us; speedup 1.0000x reference)
//
#include <hip/hip_runtime.h>
#include <hip/hip_bf16.h>
#include <math.h>

// Problem constants (from reference)
#define V_SZ 500000
#define E_SZ 128
#define H_SZ 128
#define L_SZ 10
#define P_SZ 10
#define N_SZ 50
#define B_SZ (1 + P_SZ + N_SZ)   // 61 sequences
#define TPB  128                 // 2 waves; thread t owns gate rows t, t+128, t+256

__device__ __forceinline__ float sigmoidf(float x) {
    return 1.0f / (1.0f + expf(-x));
}

__device__ __forceinline__ float dot4(const float4 a, const float4 b) {
    return a.x * b.x + a.y * b.y + a.z * b.z + a.w * b.w;
}

// One block per sequence, 128 threads. Thread t computes hidden unit t:
// it owns w rows {t, t+128, t+256} (r,z,n gates) in registers, so the gate
// nonlinearity needs NO cross-thread exchange — LDS is only xs + hs.
__global__ __launch_bounds__(TPB, 1) void gru_encode(
    const int*   __restrict__ phr_inds,   // [L]
    const int*   __restrict__ pos_inds,   // [P][L]
    const int*   __restrict__ neg_inds,   // [N][L]
    const float* __restrict__ u_emb,      // [V][E]
    const float* __restrict__ v_emb,      // [V][E]
    const float* __restrict__ w_ih,       // [3H][E]
    const float* __restrict__ w_hh,       // [3H][H]
    const float* __restrict__ b_ih,       // [3H]
    const float* __restrict__ b_hh,       // [3H]
    const float* __restrict__ h0,         // [H]
    float*       __restrict__ enc)        // [B][H] (workspace)
{
    __shared__ __align__(16) float xs[L_SZ][E_SZ];   // gathered input rows (5 KB)
    __shared__ __align__(16) float hs[2][H_SZ];      // double-buffered hidden (1 KB)

    const int b = blockIdx.x;
    const int t = threadIdx.x;

    // ---- gather x = emb[idx] into LDS (320 float4 loads over 128 threads) ----
    {
        const float* emb = (b == 0) ? u_emb : v_emb;
        #pragma unroll
        for (int i = t; i < L_SZ * (E_SZ / 4); i += TPB) {
            const int l  = i >> 5;          // / (E/4)
            const int e4 = i & 31;
            int idx;
            if (b == 0)            idx = phr_inds[l];
            else if (b <= P_SZ)    idx = pos_inds[(b - 1) * L_SZ + l];
            else                   idx = neg_inds[(b - 1 - P_SZ) * L_SZ + l];
            reinterpret_cast<float4*>(&xs[l][0])[e4] =
                reinterpret_cast<const float4*>(emb + (size_t)idx * E_SZ)[e4];
        }
    }
    hs[0][t] = h0[t];

    float bhh[3];
    float gi[3][L_SZ];   // per-step input gates, lives in registers all along
    #pragma unroll
    for (int r = 0; r < 3; ++r) {
        bhh[r] = b_hh[t + r * H_SZ];
        #pragma unroll
        for (int l = 0; l < L_SZ; ++l) gi[r][l] = 0.0f;
    }

    // ---- load this thread's 3 w_ih rows into registers ----
    float4 w3[3][E_SZ / 4];   // 384 VGPRs, all indexing compile-time
    #pragma unroll
    for (int r = 0; r < 3; ++r) {
        const float4* p = reinterpret_cast<const float4*>(w_ih + (size_t)(t + r * H_SZ) * E_SZ);
        #pragma unroll
        for (int j = 0; j < E_SZ / 4; ++j) w3[r][j] = p[j];
    }
    __syncthreads();   // xs, hs[0] visible

    // ---- gi[r][l] = x[l] . w_ih[row r] ; each xv LDS read reused 3x ----
    #pragma unroll
    for (int j = 0; j < E_SZ / 4; ++j) {
        #pragma unroll
        for (int l = 0; l < L_SZ; ++l) {
            const float4 xv = reinterpret_cast<const float4*>(&xs[l][0])[j];  // broadcast
            #pragma unroll
            for (int r = 0; r < 3; ++r) gi[r][l] += dot4(w3[r][j], xv);
        }
    }
    #pragma unroll
    for (int r = 0; r < 3; ++r) {
        const float bih = b_ih[t + r * H_SZ];
        #pragma unroll
        for (int l = 0; l < L_SZ; ++l) gi[r][l] += bih;
    }

    // ---- swap register weights to this thread's 3 w_hh rows ----
    #pragma unroll
    for (int r = 0; r < 3; ++r) {
        const float4* p = reinterpret_cast<const float4*>(w_hh + (size_t)(t + r * H_SZ) * E_SZ);
        #pragma unroll
        for (int j = 0; j < E_SZ / 4; ++j) w3[r][j] = p[j];
    }

    // ---- recurrent steps: 1 barrier/step, zero LDS exchange for gates ----
    int cur = 0;
    float hnew = 0.0f;
    #pragma unroll
    for (int l = 0; l < L_SZ; ++l) {
        const float4* hv4 = reinterpret_cast<const float4*>(&hs[cur][0]);
        // 6 accumulator chains (2 per gate row) — VALU-issue bound, dep hidden
        float a00 = 0.f, a01 = 0.f, a10 = 0.f, a11 = 0.f, a20 = 0.f, a21 = 0.f;
        #pragma unroll
        for (int j = 0; j < H_SZ / 4; j += 2) {
            const float4 x0 = hv4[j];       // broadcast LDS read, used 3x
            const float4 x1 = hv4[j + 1];
            a00 += dot4(w3[0][j], x0);  a01 += dot4(w3[0][j + 1], x1);
            a10 += dot4(w3[1][j], x0);  a11 += dot4(w3[1][j + 1], x1);
            a20 += dot4(w3[2][j], x0);  a21 += dot4(w3[2][j + 1], x1);
        }
        const float gh_r = bhh[0] + (a00 + a01);
        const float gh_z = bhh[1] + (a10 + a11);
        const float gh_n = bhh[2] + (a20 + a21);

        const float r = sigmoidf(gi[0][l] + gh_r);
        const float z = sigmoidf(gi[1][l] + gh_z);
        const float n = tanhf  (gi[2][l] + r * gh_n);
        hnew = (1.0f - z) * n + z * hs[cur][t];

        hs[cur ^ 1][t] = hnew;
        __syncthreads();              // hs[cur^1] visible; old hs free for next write
        cur ^= 1;
    }

    enc[(size_t)b * H_SZ + t] = hnew;
}

// Single wave: lane j handles enc row 1+j (10 pos + 50 neg = 60 rows)
__global__ __launch_bounds__(64) void loss_kernel(
    const float* __restrict__ enc,   // [B][H]
    float* __restrict__ out)         // f32 scalar (reference output dtype)
{
    __shared__ __align__(16) float node[H_SZ];
    const int t = threadIdx.x;
    node[t]      = enc[t];
    node[t + 64] = enc[t + 64];
    __syncthreads();

    float vp = 0.0f, vn = 0.0f;
    if (t < P_SZ + N_SZ) {
        const float4* row4 = reinterpret_cast<const float4*>(enc + (size_t)(1 + t) * H_SZ);
        float s = 0.0f;
        #pragma unroll 8
        for (int i4 = 0; i4 < H_SZ / 4; ++i4) {
            s += dot4(reinterpret_cast<const float4*>(node)[i4], row4[i4]);
        }
        s *= (1.0f / (float)H_SZ);
        if (t < P_SZ) vp = s;                               // pos dot
        else          vn = (s > 0.0f) ? expf(s) : 0.0f;     // exp(s)*(s>0)
    }

    #pragma unroll
    for (int off = 32; off > 0; off >>= 1) {
        vp += __shfl_down(vp, off);
        vn += __shfl_down(vn, off);
    }
    if (t == 0) {
        out[0] = logf(1.0f + vn) - vp;   // -(neg_loss + pos_loss)
    }
}

extern "C" void kernel_launch(void* const* d_in, const int* in_sizes, int n_in,
                              void* d_out, int out_size, void* d_ws, size_t ws_size,
                              hipStream_t stream) {
    const int*   phr_inds = (const int*)  d_in[0];
    const int*   pos_inds = (const int*)  d_in[1];
    const int*   neg_inds = (const int*)  d_in[2];
    const float* u_emb    = (const float*)d_in[3];
    const float* v_emb    = (const float*)d_in[4];
    const float* w_ih     = (const float*)d_in[5];
    const float* w_hh     = (const float*)d_in[6];
    const float* b_ih     = (const float*)d_in[7];
    const float* b_hh     = (const float*)d_in[8];
    const float* h0       = (const float*)d_in[9];

    float* enc = (float*)d_ws;   // [B][H] = 61*128 floats

    gru_encode<<<B_SZ, TPB, 0, stream>>>(phr_inds, pos_inds, neg_inds,
                                         u_emb, v_emb, w_ih, w_hh, b_ih, b_hh, h0,
                                         enc);
    loss_kernel<<<1, 64, 0, stream>>>(enc, (float*)d_out);
}

// Round 9
// 41.602 us; speedup vs baseline: 9.3297x; 9.3297x over previous
//
#include <hip/hip_runtime.h>
#include <hip/hip_bf16.h>
#include <math.h>

// Problem constants (from reference)
#define V_SZ 500000
#define E_SZ 128
#define H_SZ 128
#define L_SZ 10
#define P_SZ 10
#define N_SZ 50
#define B_SZ (1 + P_SZ + N_SZ)   // 61 sequences
#define G_SZ (3 * H_SZ)          // 384 gate outputs

// Flag handshake for fused loss (last-block pattern, replay-idempotent)
#define FLAG_STRIDE 16               // one flag per 64 B to avoid line contention
#define FLAG_MAGIC  0x9E370000u     // flags[b] == FLAG_MAGIC + b when row b is published

__device__ __forceinline__ float sigmoidf(float x) {
    return 1.0f / (1.0f + expf(-x));
}

__device__ __forceinline__ float dot4(const float4 a, const float4 b) {
    return a.x * b.x + a.y * b.y + a.z * b.z + a.w * b.w;
}

// One block per sequence. 384 threads: thread t owns gate row g = t
// (32 float4 = 128 VGPRs of weights — round-8 lesson: 3 rows/thread spills,
// the allocator caps at 256 arch VGPRs).
// Block 0 additionally computes the scalar loss after all blocks publish.
__global__ __launch_bounds__(G_SZ) void gru_fused(
    const int*   __restrict__ phr_inds,   // [L]
    const int*   __restrict__ pos_inds,   // [P][L]
    const int*   __restrict__ neg_inds,   // [N][L]
    const float* __restrict__ u_emb,      // [V][E]
    const float* __restrict__ v_emb,      // [V][E]
    const float* __restrict__ w_ih,       // [3H][E]
    const float* __restrict__ w_hh,       // [3H][H]
    const float* __restrict__ b_ih,       // [3H]
    const float* __restrict__ b_hh,       // [3H]
    const float* __restrict__ h0,         // [H]
    float*       __restrict__ enc,        // [B][H] (workspace)
    unsigned*    __restrict__ flags,      // [B*FLAG_STRIDE] (workspace)
    float*       __restrict__ out)        // f32 scalar
{
    __shared__ __align__(16) float xs[L_SZ][E_SZ];     // gathered input rows (5 KB)
    __shared__ __align__(16) float gi_all[L_SZ][G_SZ]; // gi + b_ih, all steps (15 KB)
    __shared__ __align__(16) float hs[2][H_SZ];        // double-buffered hidden
    __shared__ __align__(16) float gh_s[G_SZ];         // gh exchange

    const int b = blockIdx.x;
    const int t = threadIdx.x;

    // ---- gather x = emb[idx] into LDS (320 float4 loads) ----
    if (t < L_SZ * (E_SZ / 4)) {
        const float* emb = (b == 0) ? u_emb : v_emb;
        const int l  = t >> 5;          // / (E/4)
        const int e4 = t & 31;
        int idx;
        if (b == 0)            idx = phr_inds[l];
        else if (b <= P_SZ)    idx = pos_inds[(b - 1) * L_SZ + l];
        else                   idx = neg_inds[(b - 1 - P_SZ) * L_SZ + l];
        reinterpret_cast<float4*>(&xs[l][0])[e4] =
            reinterpret_cast<const float4*>(emb + (size_t)idx * E_SZ)[e4];
    }
    if (t < H_SZ) hs[0][t] = h0[t];

    const float bih = b_ih[t];
    const float bhh = b_hh[t];

    // ---- load w_ih row into registers while the gather lands ----
    float4 wreg[E_SZ / 4];                 // 128 VGPRs, static indexing only
    {
        const float4* wih4 = reinterpret_cast<const float4*>(w_ih + (size_t)t * E_SZ);
        #pragma unroll
        for (int j = 0; j < E_SZ / 4; ++j) wreg[j] = wih4[j];
    }
    __syncthreads();   // xs, hs[0] visible

    // ---- gi[l][g] = x[l] . w_ih[g] + b_ih[g], all 10 steps at once ----
    {
        float gacc[L_SZ];
        #pragma unroll
        for (int l = 0; l < L_SZ; ++l) gacc[l] = 0.0f;

        #pragma unroll
        for (int j = 0; j < E_SZ / 4; ++j) {
            const float4 w = wreg[j];
            #pragma unroll
            for (int l = 0; l < L_SZ; ++l) {
                const float4 xv = reinterpret_cast<const float4*>(&xs[l][0])[j];  // broadcast
                gacc[l] += dot4(w, xv);
            }
        }
        #pragma unroll
        for (int l = 0; l < L_SZ; ++l) gi_all[l][t] = gacc[l] + bih;
    }

    // ---- swap register weights to the w_hh row ----
    {
        const float4* whh4 = reinterpret_cast<const float4*>(w_hh + (size_t)t * H_SZ);
        #pragma unroll
        for (int j = 0; j < H_SZ / 4; ++j) wreg[j] = whh4[j];
    }
    __syncthreads();   // gi_all visible

    // ---- recurrent steps: 2 barriers/step, zero global loads ----
    int cur = 0;
    float hnew = 0.0f;
    for (int l = 0; l < L_SZ; ++l) {
        const float4* hv4 = reinterpret_cast<const float4*>(&hs[cur][0]);
        float a0 = 0.0f, a1 = 0.0f, a2 = 0.0f, a3 = 0.0f;   // 4 chains for ILP
        #pragma unroll
        for (int j = 0; j < H_SZ / 4; j += 4) {
            a0 += dot4(wreg[j    ], hv4[j    ]);
            a1 += dot4(wreg[j + 1], hv4[j + 1]);
            a2 += dot4(wreg[j + 2], hv4[j + 2]);
            a3 += dot4(wreg[j + 3], hv4[j + 3]);
        }
        gh_s[t] = bhh + ((a0 + a1) + (a2 + a3));
        __syncthreads();                       // [A] gh_s visible

        if (t < H_SZ) {
            const float r = sigmoidf(gi_all[l][t]           + gh_s[t]);
            const float z = sigmoidf(gi_all[l][t +   H_SZ]  + gh_s[t +   H_SZ]);
            const float n = tanhf  (gi_all[l][t + 2*H_SZ]  + r * gh_s[t + 2*H_SZ]);
            hnew = (1.0f - z) * n + z * hs[cur][t];
            hs[cur ^ 1][t] = hnew;
        }
        __syncthreads();                       // [B] hs[cur^1] visible
        cur ^= 1;
    }
    // final hidden state lives in hs[cur] (cur == 0 after 10 steps)

    if (t < H_SZ) enc[(size_t)b * H_SZ + t] = hnew;

    // ---- publish / consume ----
    if (b != 0) {
        __syncthreads();                       // all enc writes of this block done
        if (t == 0) {
            __threadfence();                   // flush to device-coherent point
            atomicExch(&flags[b * FLAG_STRIDE], FLAG_MAGIC + (unsigned)b);  // device-scope
        }
        return;
    }

    // block 0, wave 0: wait for the 60 other rows, then compute the loss.
    if (t >= 64) return;

    if (t < P_SZ + N_SZ) {
        const unsigned want = FLAG_MAGIC + 1u + (unsigned)t;
        while (atomicAdd(&flags[(1 + t) * FLAG_STRIDE], 0u) != want) {  // coherent read
            __builtin_amdgcn_s_sleep(2);
        }
    }
    __threadfence();   // acquire side: order enc reads after flag observation

    float vp = 0.0f, vn = 0.0f;
    if (t < P_SZ + N_SZ) {
        const float4* row4  = reinterpret_cast<const float4*>(enc + (size_t)(1 + t) * H_SZ);
        const float4* node4 = reinterpret_cast<const float4*>(&hs[cur][0]);  // own final h (LDS)
        float s = 0.0f;
        #pragma unroll 8
        for (int i4 = 0; i4 < H_SZ / 4; ++i4) {
            s += dot4(node4[i4], row4[i4]);
        }
        s *= (1.0f / (float)H_SZ);
        if (t < P_SZ) vp = s;                               // pos dot
        else          vn = (s > 0.0f) ? expf(s) : 0.0f;     // exp(s)*(s>0)
    }

    #pragma unroll
    for (int off = 32; off > 0; off >>= 1) {
        vp += __shfl_down(vp, off);
        vn += __shfl_down(vn, off);
    }
    if (t == 0) {
        out[0] = logf(1.0f + vn) - vp;   // -(neg_loss + pos_loss)
    }
}

extern "C" void kernel_launch(void* const* d_in, const int* in_sizes, int n_in,
                              void* d_out, int out_size, void* d_ws, size_t ws_size,
                              hipStream_t stream) {
    const int*   phr_inds = (const int*)  d_in[0];
    const int*   pos_inds = (const int*)  d_in[1];
    const int*   neg_inds = (const int*)  d_in[2];
    const float* u_emb    = (const float*)d_in[3];
    const float* v_emb    = (const float*)d_in[4];
    const float* w_ih     = (const float*)d_in[5];
    const float* w_hh     = (const float*)d_in[6];
    const float* b_ih     = (const float*)d_in[7];
    const float* b_hh     = (const float*)d_in[8];
    const float* h0       = (const float*)d_in[9];

    float*    enc   = (float*)d_ws;                               // [B][H] floats
    unsigned* flags = (unsigned*)((char*)d_ws + 32768);           // cache-line separated

    gru_fused<<<B_SZ, G_SZ, 0, stream>>>(phr_inds, pos_inds, neg_inds,
                                         u_emb, v_emb, w_ih, w_hh, b_ih, b_hh, h0,
                                         enc, flags, (float*)d_out);
}

// Round 10
// 34.342 us; speedup vs baseline: 11.3018x; 1.2114x over previous
//
#include <hip/hip_runtime.h>
#include <hip/hip_bf16.h>
#include <math.h>

// Problem constants (from reference)
#define V_SZ 500000
#define E_SZ 128
#define H_SZ 128
#define L_SZ 10
#define P_SZ 10
#define N_SZ 50
#define B_SZ (1 + P_SZ + N_SZ)   // 61 sequences
#define TPB  384                 // 6 waves; wave w owns gate rows [64w, 64w+64)

#define FLAG_STRIDE 16
#define FLAG_MAGIC  0x9E370000u

#define GI_STR 388               // gi_all row stride (floats): 388%32=4 -> ~2-way banks, 16B-aligned
#define XS_STR 136               // xs_bf16 row stride (bf16):  272B, 16B-aligned

typedef __attribute__((ext_vector_type(8))) short bf16x8;  // 8 bf16 = 4 VGPRs (MFMA A/B frag)
typedef __attribute__((ext_vector_type(4))) float f32x4;   // MFMA C/D frag

#define MFMA(a, b, c) __builtin_amdgcn_mfma_f32_16x16x32_bf16((a), (b), (c), 0, 0, 0)

__device__ __forceinline__ float sigmoidf(float x) {
    return 1.0f / (1.0f + expf(-x));
}

__device__ __forceinline__ unsigned short f2bf(float f) {   // RNE f32 -> bf16
    unsigned u = __float_as_uint(f);
    u += 0x7FFFu + ((u >> 16) & 1u);
    return (unsigned short)(u >> 16);
}

__device__ __forceinline__ bf16x8 pack8(float4 a, float4 b) {
    bf16x8 r;
    r[0] = (short)f2bf(a.x); r[1] = (short)f2bf(a.y);
    r[2] = (short)f2bf(a.z); r[3] = (short)f2bf(a.w);
    r[4] = (short)f2bf(b.x); r[5] = (short)f2bf(b.y);
    r[6] = (short)f2bf(b.z); r[7] = (short)f2bf(b.w);
    return r;
}

// One block per sequence, 384 threads (6 waves).
// A-frags (W_ih, W_hh as bf16) live in registers: 16 frags x 4 VGPR x 2 mats = 128 VGPR.
// Per step: gates(384) = W_hh @ h via 16 MFMA/wave; h broadcast as identical B columns.
// Gate nonlinearity on t<128 (h carried in f32 register), h re-broadcast via bf16 LDS.
__global__ __launch_bounds__(TPB) void gru_fused(
    const int*   __restrict__ phr_inds,
    const int*   __restrict__ pos_inds,
    const int*   __restrict__ neg_inds,
    const float* __restrict__ u_emb,
    const float* __restrict__ v_emb,
    const float* __restrict__ w_ih,
    const float* __restrict__ w_hh,
    const float* __restrict__ b_ih,
    const float* __restrict__ b_hh,
    const float* __restrict__ h0,
    float*       __restrict__ enc,      // [B][H] workspace
    unsigned*    __restrict__ flags,    // [B*FLAG_STRIDE] workspace
    float*       __restrict__ out)      // f32 scalar
{
    __shared__ __align__(16) unsigned short xs_bf16[16 * XS_STR]; // x^T as B operand (rows 10..15 zero)
    __shared__ __align__(16) float          gi_all[16 * GI_STR];  // gi[col=l][row=g]
    __shared__ __align__(16) float          gh_s[3 * H_SZ];       // gh exchange; node buffer at the end
    __shared__ __align__(16) unsigned short hs_bf16[H_SZ];        // h broadcast (bf16)

    const int b    = blockIdx.x;
    const int t    = threadIdx.x;
    const int lane = t & 63;
    const int wv   = t >> 6;                 // wave 0..5
    const int kg   = lane >> 4;              // k-group 0..3
    const int col  = lane & 15;              // B/D column for this lane
    const int arow = wv * 64 + col;          // A row (lane&15 = row within 16-block)

    // ---- gather x rows -> xs_bf16 (deepest-latency loads, issue first) ----
    if (t < L_SZ * 32) {
        const int l  = t >> 5;
        const int e4 = t & 31;
        int idx; const float* emb;
        if (b == 0)         { idx = phr_inds[l];                    emb = u_emb; }
        else if (b <= P_SZ) { idx = pos_inds[(b - 1) * L_SZ + l];   emb = v_emb; }
        else                { idx = neg_inds[(b - 1 - P_SZ) * L_SZ + l]; emb = v_emb; }
        const float4 v = *reinterpret_cast<const float4*>(emb + (size_t)idx * E_SZ + e4 * 4);
        short4 s4;
        s4.x = (short)f2bf(v.x); s4.y = (short)f2bf(v.y);
        s4.z = (short)f2bf(v.z); s4.w = (short)f2bf(v.w);
        *reinterpret_cast<short4*>((char*)xs_bf16 + l * (XS_STR * 2) + e4 * 8) = s4;
    }
    // zero-fill B columns 10..15 (6 rows x 136 bf16 = 1632 B = 102 x 16B)
    if (t < 102) {
        bf16x8 z8 = {0, 0, 0, 0, 0, 0, 0, 0};
        *reinterpret_cast<bf16x8*>((char*)xs_bf16 + 10 * (XS_STR * 2) + t * 16) = z8;
    }

    // ---- load W_ih / W_hh A-fragments into registers (bf16) ----
    bf16x8 aih[4][4], ahh[4][4];
    #pragma unroll
    for (int mb = 0; mb < 4; ++mb) {
        const float* pi = w_ih + (size_t)(arow + mb * 16) * E_SZ + kg * 8;
        const float* ph = w_hh + (size_t)(arow + mb * 16) * H_SZ + kg * 8;
        #pragma unroll
        for (int kb = 0; kb < 4; ++kb) {
            const float4 l1 = *reinterpret_cast<const float4*>(pi + kb * 32);
            const float4 h1 = *reinterpret_cast<const float4*>(pi + kb * 32 + 4);
            aih[mb][kb] = pack8(l1, h1);
            const float4 l2 = *reinterpret_cast<const float4*>(ph + kb * 32);
            const float4 h2 = *reinterpret_cast<const float4*>(ph + kb * 32 + 4);
            ahh[mb][kb] = pack8(l2, h2);
        }
    }

    // ---- biases + h0 (gate threads only) ----
    float bih_r = 0.f, bih_z = 0.f, bih_n = 0.f;
    float bhh_r = 0.f, bhh_z = 0.f, bhh_n = 0.f;
    float h_reg = 0.f;
    if (t < H_SZ) {
        bih_r = b_ih[t]; bih_z = b_ih[t + 128]; bih_n = b_ih[t + 256];
        bhh_r = b_hh[t]; bhh_z = b_hh[t + 128]; bhh_n = b_hh[t + 256];
        h_reg = h0[t];
        hs_bf16[t] = f2bf(h_reg);
    }
    __syncthreads();   // xs_bf16, hs_bf16 visible

    // ---- gi = W_ih @ X^T in ONE MFMA pass (cols = steps l) ----
    {
        f32x4 g0 = {0.f,0.f,0.f,0.f}, g1 = {0.f,0.f,0.f,0.f};
        f32x4 g2 = {0.f,0.f,0.f,0.f}, g3 = {0.f,0.f,0.f,0.f};
        #pragma unroll
        for (int kb = 0; kb < 4; ++kb) {
            const bf16x8 xb = *reinterpret_cast<const bf16x8*>(
                (const char*)xs_bf16 + col * (XS_STR * 2) + kb * 64 + kg * 16);
            g0 = MFMA(aih[0][kb], xb, g0);
            g1 = MFMA(aih[1][kb], xb, g1);
            g2 = MFMA(aih[2][kb], xb, g2);
            g3 = MFMA(aih[3][kb], xb, g3);
        }
        const int rb = wv * 64 + kg * 4;     // D row base: (lane>>4)*4 + reg (m89-verified)
        *reinterpret_cast<f32x4*>(&gi_all[col * GI_STR + rb     ]) = g0;
        *reinterpret_cast<f32x4*>(&gi_all[col * GI_STR + rb + 16]) = g1;
        *reinterpret_cast<f32x4*>(&gi_all[col * GI_STR + rb + 32]) = g2;
        *reinterpret_cast<f32x4*>(&gi_all[col * GI_STR + rb + 48]) = g3;
    }
    // no barrier needed: step-0 barrier [A] orders gi_all writes before gate reads

    // ---- recurrent steps: 4 broadcast LDS reads + 16 MFMA per wave per step ----
    for (int l = 0; l < L_SZ; ++l) {
        f32x4 a0 = {0.f,0.f,0.f,0.f}, a1 = {0.f,0.f,0.f,0.f};
        f32x4 a2 = {0.f,0.f,0.f,0.f}, a3 = {0.f,0.f,0.f,0.f};
        #pragma unroll
        for (int kb = 0; kb < 4; ++kb) {
            // every lane reads its k-slice of h; all 16 cols get identical data
            const bf16x8 bh = *reinterpret_cast<const bf16x8*>(
                (const char*)hs_bf16 + kb * 64 + kg * 16);
            a0 = MFMA(ahh[0][kb], bh, a0);
            a1 = MFMA(ahh[1][kb], bh, a1);
            a2 = MFMA(ahh[2][kb], bh, a2);
            a3 = MFMA(ahh[3][kb], bh, a3);
        }
        if (col == 0) {                       // col-0 lanes hold gh for the wave's 64 rows
            const int rb = wv * 64 + kg * 4;
            *reinterpret_cast<f32x4*>(&gh_s[rb     ]) = a0;
            *reinterpret_cast<f32x4*>(&gh_s[rb + 16]) = a1;
            *reinterpret_cast<f32x4*>(&gh_s[rb + 32]) = a2;
            *reinterpret_cast<f32x4*>(&gh_s[rb + 48]) = a3;
        }
        __syncthreads();                      // [A] gh_s (and, at l==0, gi_all) visible

        if (t < H_SZ) {
            const float r = sigmoidf(gi_all[l * GI_STR + t      ] + bih_r + (gh_s[t      ] + bhh_r));
            const float z = sigmoidf(gi_all[l * GI_STR + t + 128] + bih_z + (gh_s[t + 128] + bhh_z));
            const float n = tanhf  (gi_all[l * GI_STR + t + 256] + bih_n + r * (gh_s[t + 256] + bhh_n));
            h_reg = (1.0f - z) * n + z * h_reg;
            if (l < L_SZ - 1) hs_bf16[t] = f2bf(h_reg);  // re-broadcast for next step
            else              gh_s[t]   = h_reg;         // final h -> node buffer (f32)
        }
        __syncthreads();                      // [B] hs_bf16 / node visible
    }

    if (t < H_SZ) enc[(size_t)b * H_SZ + t] = h_reg;

    // ---- publish / consume (round-9 validated pattern) ----
    if (b != 0) {
        __syncthreads();                      // block's enc stores drained (vmcnt at barrier)
        if (t == 0) {
            __threadfence();
            atomicExch(&flags[b * FLAG_STRIDE], FLAG_MAGIC + (unsigned)b);
        }
        return;
    }

    if (t >= 64) return;                      // no further barriers below

    if (t < P_SZ + N_SZ) {
        const unsigned want = FLAG_MAGIC + 1u + (unsigned)t;
        while (atomicAdd(&flags[(1 + t) * FLAG_STRIDE], 0u) != want) {
            __builtin_amdgcn_s_sleep(2);
        }
    }
    __threadfence();   // acquire: order enc reads after flag observation

    float vp = 0.0f, vn = 0.0f;
    if (t < P_SZ + N_SZ) {
        const float4* row4  = reinterpret_cast<const float4*>(enc + (size_t)(1 + t) * H_SZ);
        const float4* node4 = reinterpret_cast<const float4*>(&gh_s[0]);   // final h of seq 0
        float s = 0.0f;
        #pragma unroll 8
        for (int i4 = 0; i4 < H_SZ / 4; ++i4) {
            const float4 nn = node4[i4];
            const float4 rr = row4[i4];
            s += nn.x * rr.x + nn.y * rr.y + nn.z * rr.z + nn.w * rr.w;
        }
        s *= (1.0f / (float)H_SZ);
        if (t < P_SZ) vp = s;
        else          vn = (s > 0.0f) ? expf(s) : 0.0f;
    }

    #pragma unroll
    for (int off = 32; off > 0; off >>= 1) {
        vp += __shfl_down(vp, off);
        vn += __shfl_down(vn, off);
    }
    if (t == 0) {
        out[0] = logf(1.0f + vn) - vp;   // -(neg_loss + pos_loss)
    }
}

extern "C" void kernel_launch(void* const* d_in, const int* in_sizes, int n_in,
                              void* d_out, int out_size, void* d_ws, size_t ws_size,
                              hipStream_t stream) {
    const int*   phr_inds = (const int*)  d_in[0];
    const int*   pos_inds = (const int*)  d_in[1];
    const int*   neg_inds = (const int*)  d_in[2];
    const float* u_emb    = (const float*)d_in[3];
    const float* v_emb    = (const float*)d_in[4];
    const float* w_ih     = (const float*)d_in[5];
    const float* w_hh     = (const float*)d_in[6];
    const float* b_ih     = (const float*)d_in[7];
    const float* b_hh     = (const float*)d_in[8];
    const float* h0       = (const float*)d_in[9];

    float*    enc   = (float*)d_ws;                       // [B][H] floats (31 KB)
    unsigned* flags = (unsigned*)((char*)d_ws + 32768);   // separate region

    gru_fused<<<B_SZ, TPB, 0, stream>>>(phr_inds, pos_inds, neg_inds,
                                        u_emb, v_emb, w_ih, w_hh, b_ih, b_hh, h0,
                                        enc, flags, (float*)d_out);
}

// Round 11
// 32.305 us; speedup vs baseline: 12.0144x; 1.0630x over previous
//
#include <hip/hip_runtime.h>
#include <hip/hip_bf16.h>
#include <math.h>

// Problem constants (from reference)
#define V_SZ 500000
#define E_SZ 128
#define H_SZ 128
#define L_SZ 10
#define P_SZ 10
#define N_SZ 50
#define NSEQ (P_SZ + N_SZ)       // 60 non-phrase sequences
#define NBLK 60                  // block j handles (seq 0, seq j+1)
#define TPB  384                 // 6 waves; wave w owns gate rows [64w, 64w+64)

#define FLAG_STRIDE 16
#define SLOT_STRIDE 16
#define FLAG_MAGIC  0x9E370000u

#define GI_STR 388               // gi_all row stride (floats): 16B-aligned, ~2-way banks
#define XS_STR 136               // xs_bf16 row stride (bf16): 272B, 16B-aligned

typedef __attribute__((ext_vector_type(8))) short bf16x8;  // 8 bf16 = 4 VGPRs (MFMA A/B frag)
typedef __attribute__((ext_vector_type(4))) float f32x4;   // MFMA C/D frag

#define MFMA(a, b, c) __builtin_amdgcn_mfma_f32_16x16x32_bf16((a), (b), (c), 0, 0, 0)

__device__ __forceinline__ float sigmoidf(float x) {
    return 1.0f / (1.0f + expf(-x));
}

__device__ __forceinline__ unsigned short f2bf(float f) {   // RNE f32 -> bf16
    unsigned u = __float_as_uint(f);
    u += 0x7FFFu + ((u >> 16) & 1u);
    return (unsigned short)(u >> 16);
}

__device__ __forceinline__ bf16x8 pack8(float4 a, float4 b) {
    bf16x8 r;
    r[0] = (short)f2bf(a.x); r[1] = (short)f2bf(a.y);
    r[2] = (short)f2bf(a.z); r[3] = (short)f2bf(a.w);
    r[4] = (short)f2bf(b.x); r[5] = (short)f2bf(b.y);
    r[6] = (short)f2bf(b.z); r[7] = (short)f2bf(b.w);
    return r;
}

// Block j processes TWO sequences through the same MFMAs:
//   B-column parity 0 = sequence 0 (recomputed identically by every block),
//   B-column parity 1 = sequence j+1.
// At the end each block computes s = (h_seq0 . h_seqB)/128 locally and
// publishes the SCALAR; block 0 aggregates 60 scalars into the loss.
__global__ __launch_bounds__(TPB) void gru_fused(
    const int*   __restrict__ phr_inds,
    const int*   __restrict__ pos_inds,
    const int*   __restrict__ neg_inds,
    const float* __restrict__ u_emb,
    const float* __restrict__ v_emb,
    const float* __restrict__ w_ih,
    const float* __restrict__ w_hh,
    const float* __restrict__ b_ih,
    const float* __restrict__ b_hh,
    const float* __restrict__ h0,
    float*       __restrict__ slots,    // [NBLK*SLOT_STRIDE] workspace (s scalars)
    unsigned*    __restrict__ flags,    // [NBLK*FLAG_STRIDE] workspace
    float*       __restrict__ out)      // f32 scalar
{
    __shared__ __align__(16) unsigned short xs_bf16[2][16 * XS_STR]; // x^T per seq-group
    __shared__ __align__(16) float          gi_all[2][16 * GI_STR];  // gi[seq][col=l][row=g]
    __shared__ __align__(16) float          gh_s[2][3 * H_SZ];       // gh exchange per seq
    __shared__ __align__(16) unsigned short hs_bf16[2][H_SZ];        // h broadcast per seq
    __shared__ __align__(16) float          node[2][H_SZ];           // final h (f32) per seq

    const int bj   = blockIdx.x;             // 0..59
    const int seqB = bj + 1;                 // enc row this block owns (1..60)
    const int t    = threadIdx.x;
    const int lane = t & 63;
    const int wv   = t >> 6;                 // wave 0..5
    const int kg   = lane >> 4;              // k-group 0..3
    const int col  = lane & 15;              // B/D column for this lane
    const int arow = wv * 64 + col;          // A row (lane&15 = row within 16-block)

    // ---- gather x rows for BOTH sequences (deepest-latency loads first) ----
    for (int i = t; i < 2 * L_SZ * 32; i += TPB) {
        const int r  = i >> 5;               // 0..19
        const int e4 = i & 31;
        const int g  = (r < L_SZ) ? 0 : 1;
        const int l  = (r < L_SZ) ? r : r - L_SZ;
        int idx; const float* emb;
        if (g == 0)             { idx = phr_inds[l];                       emb = u_emb; }
        else if (seqB <= P_SZ)  { idx = pos_inds[(seqB - 1) * L_SZ + l];   emb = v_emb; }
        else                    { idx = neg_inds[(seqB - 1 - P_SZ) * L_SZ + l]; emb = v_emb; }
        const float4 v = *reinterpret_cast<const float4*>(emb + (size_t)idx * E_SZ + e4 * 4);
        short4 s4;
        s4.x = (short)f2bf(v.x); s4.y = (short)f2bf(v.y);
        s4.z = (short)f2bf(v.z); s4.w = (short)f2bf(v.w);
        *reinterpret_cast<short4*>((char*)&xs_bf16[g][0] + l * (XS_STR * 2) + e4 * 8) = s4;
    }
    // (cols 10..15 of each group left uninitialized: their gi outputs are never read)

    // ---- load W_ih / W_hh A-fragments into registers (bf16) ----
    bf16x8 aih[4][4], ahh[4][4];
    #pragma unroll
    for (int mb = 0; mb < 4; ++mb) {
        const float* pi = w_ih + (size_t)(arow + mb * 16) * E_SZ + kg * 8;
        const float* ph = w_hh + (size_t)(arow + mb * 16) * H_SZ + kg * 8;
        #pragma unroll
        for (int kb = 0; kb < 4; ++kb) {
            const float4 l1 = *reinterpret_cast<const float4*>(pi + kb * 32);
            const float4 h1 = *reinterpret_cast<const float4*>(pi + kb * 32 + 4);
            aih[mb][kb] = pack8(l1, h1);
            const float4 l2 = *reinterpret_cast<const float4*>(ph + kb * 32);
            const float4 h2 = *reinterpret_cast<const float4*>(ph + kb * 32 + 4);
            ahh[mb][kb] = pack8(l2, h2);
        }
    }

    // ---- biases + h0 (gate threads: t<256, seq=t>>7, unit=t&127) ----
    const int gseq = t >> 7;                 // 0 or 1 (for t<256)
    const int gu   = t & 127;
    float bih_r = 0.f, bih_z = 0.f, bih_n = 0.f;
    float bhh_r = 0.f, bhh_z = 0.f, bhh_n = 0.f;
    float h_reg = 0.f;
    if (t < 2 * H_SZ) {
        bih_r = b_ih[gu]; bih_z = b_ih[gu + 128]; bih_n = b_ih[gu + 256];
        bhh_r = b_hh[gu]; bhh_z = b_hh[gu + 128]; bhh_n = b_hh[gu + 256];
        h_reg = h0[gu];
        hs_bf16[gseq][gu] = f2bf(h_reg);     // both groups init to h0
    }
    __syncthreads();   // xs_bf16, hs_bf16 visible

    // ---- gi = W_ih @ X^T, one MFMA pass per sequence group ----
    #pragma unroll
    for (int g = 0; g < 2; ++g) {
        f32x4 g0 = {0.f,0.f,0.f,0.f}, g1 = {0.f,0.f,0.f,0.f};
        f32x4 g2 = {0.f,0.f,0.f,0.f}, g3 = {0.f,0.f,0.f,0.f};
        #pragma unroll
        for (int kb = 0; kb < 4; ++kb) {
            const bf16x8 xb = *reinterpret_cast<const bf16x8*>(
                (const char*)&xs_bf16[g][0] + col * (XS_STR * 2) + kb * 64 + kg * 16);
            g0 = MFMA(aih[0][kb], xb, g0);
            g1 = MFMA(aih[1][kb], xb, g1);
            g2 = MFMA(aih[2][kb], xb, g2);
            g3 = MFMA(aih[3][kb], xb, g3);
        }
        const int rb = wv * 64 + kg * 4;     // D row base: (lane>>4)*4 + reg (m89-verified)
        *reinterpret_cast<f32x4*>(&gi_all[g][col * GI_STR + rb     ]) = g0;
        *reinterpret_cast<f32x4*>(&gi_all[g][col * GI_STR + rb + 16]) = g1;
        *reinterpret_cast<f32x4*>(&gi_all[g][col * GI_STR + rb + 32]) = g2;
        *reinterpret_cast<f32x4*>(&gi_all[g][col * GI_STR + rb + 48]) = g3;
    }
    // no barrier needed: step-0 barrier [A] orders gi_all writes before gate reads

    // ---- recurrent steps: 16 MFMA/wave/step, cols alternate seq0/seqB ----
    for (int l = 0; l < L_SZ; ++l) {
        f32x4 a0 = {0.f,0.f,0.f,0.f}, a1 = {0.f,0.f,0.f,0.f};
        f32x4 a2 = {0.f,0.f,0.f,0.f}, a3 = {0.f,0.f,0.f,0.f};
        #pragma unroll
        for (int kb = 0; kb < 4; ++kb) {
            // col parity selects which sequence's h this column multiplies
            const bf16x8 bh = *reinterpret_cast<const bf16x8*>(
                (const char*)&hs_bf16[col & 1][0] + kb * 64 + kg * 16);
            a0 = MFMA(ahh[0][kb], bh, a0);
            a1 = MFMA(ahh[1][kb], bh, a1);
            a2 = MFMA(ahh[2][kb], bh, a2);
            a3 = MFMA(ahh[3][kb], bh, a3);
        }
        if (col < 2) {                        // cols 0,1 hold gh for seq0 / seqB
            const int rb = wv * 64 + kg * 4;
            *reinterpret_cast<f32x4*>(&gh_s[col][rb     ]) = a0;
            *reinterpret_cast<f32x4*>(&gh_s[col][rb + 16]) = a1;
            *reinterpret_cast<f32x4*>(&gh_s[col][rb + 32]) = a2;
            *reinterpret_cast<f32x4*>(&gh_s[col][rb + 48]) = a3;
        }
        __syncthreads();                      // [A] gh_s (and, at l==0, gi_all) visible

        if (t < 2 * H_SZ) {
            const float* gi = &gi_all[gseq][l * GI_STR];
            const float* gh = &gh_s[gseq][0];
            const float r = sigmoidf(gi[gu      ] + bih_r + (gh[gu      ] + bhh_r));
            const float z = sigmoidf(gi[gu + 128] + bih_z + (gh[gu + 128] + bhh_z));
            const float n = tanhf  (gi[gu + 256] + bih_n + r * (gh[gu + 256] + bhh_n));
            h_reg = (1.0f - z) * n + z * h_reg;
            if (l < L_SZ - 1) hs_bf16[gseq][gu] = f2bf(h_reg);  // re-broadcast
            else              node[gseq][gu]   = h_reg;         // final h (f32)
        }
        __syncthreads();                      // [B] hs_bf16 / node visible
    }

    // ---- local dot: s = (node0 . node1) / 128, computed by wave 0 ----
    if (t >= 64) return;                      // no further barriers below

    float d = node[0][t] * node[1][t] + node[0][t + 64] * node[1][t + 64];
    #pragma unroll
    for (int off = 32; off > 0; off >>= 1) d += __shfl_down(d, off);
    const float s_own = d * (1.0f / (float)H_SZ);   // valid in lane 0

    // ---- publish (blocks 1..59) / aggregate (block 0) ----
    if (bj != 0) {
        if (t == 0) {
            slots[bj * SLOT_STRIDE] = s_own;   // plain store, bit-deterministic
            __threadfence();                   // release: slot visible before flag
            atomicExch(&flags[bj * FLAG_STRIDE], FLAG_MAGIC + (unsigned)bj);
        }
        return;
    }

    // block 0: lane k owns enc-row k+1. Lane 0 = own s; lanes 1..59 = block k's.
    float sv = 0.0f;
    if (t == 0) sv = s_own;
    else if (t < NSEQ) {
        const unsigned want = FLAG_MAGIC + (unsigned)t;
        while (atomicAdd(&flags[t * FLAG_STRIDE], 0u) != want) {
            __builtin_amdgcn_s_sleep(2);
        }
        __threadfence();                       // acquire: order slot read after flag
        sv = slots[t * SLOT_STRIDE];
    }

    float vp = 0.0f, vn = 0.0f;
    if (t < P_SZ)      vp = sv;                              // rows 1..10: pos
    else if (t < NSEQ) vn = (sv > 0.0f) ? expf(sv) : 0.0f;   // rows 11..60: neg

    #pragma unroll
    for (int off = 32; off > 0; off >>= 1) {
        vp += __shfl_down(vp, off);
        vn += __shfl_down(vn, off);
    }
    if (t == 0) {
        out[0] = logf(1.0f + vn) - vp;   // -(neg_loss + pos_loss)
    }
}

extern "C" void kernel_launch(void* const* d_in, const int* in_sizes, int n_in,
                              void* d_out, int out_size, void* d_ws, size_t ws_size,
                              hipStream_t stream) {
    const int*   phr_inds = (const int*)  d_in[0];
    const int*   pos_inds = (const int*)  d_in[1];
    const int*   neg_inds = (const int*)  d_in[2];
    const float* u_emb    = (const float*)d_in[3];
    const float* v_emb    = (const float*)d_in[4];
    const float* w_ih     = (const float*)d_in[5];
    const float* w_hh     = (const float*)d_in[6];
    const float* b_ih     = (const float*)d_in[7];
    const float* b_hh     = (const float*)d_in[8];
    const float* h0       = (const float*)d_in[9];

    float*    slots = (float*)d_ws;                       // s scalars (strided)
    unsigned* flags = (unsigned*)((char*)d_ws + 16384);   // separate region

    gru_fused<<<NBLK, TPB, 0, stream>>>(phr_inds, pos_inds, neg_inds,
                                        u_emb, v_emb, w_ih, w_hh, b_ih, b_hh, h0,
                                        slots, flags, (float*)d_out);
}

// Round 12
// 22.852 us; speedup vs baseline: 16.9842x; 1.4137x over previous
//
#include <hip/hip_runtime.h>
#include <hip/hip_bf16.h>
#include <math.h>

// Problem constants (from reference)
#define V_SZ 500000
#define E_SZ 128
#define H_SZ 128
#define L_SZ 10
#define P_SZ 10
#define N_SZ 50
#define NSEQ (P_SZ + N_SZ)       // 60 non-phrase sequences
#define NBLK 60                  // block j handles (seq 0, seq j+1)
#define TPB  384                 // 6 waves; wave w owns gate rows [64w, 64w+64)

#define FLAG_STRIDE 16
#define SLOT_STRIDE 16
#define FLAG_MAGIC  0x9E370000u

#define GI_STR 388               // gi_all row stride (floats): 16B-aligned, ~2-way banks
#define XS_STR 136               // xs_bf16 row stride (bf16): 272B, 16B-aligned
#define SLAB_ROWS 192            // weight staging slab (48 KB bf16)

typedef __attribute__((ext_vector_type(8))) short bf16x8;  // 8 bf16 = 4 VGPRs (MFMA A/B frag)
typedef __attribute__((ext_vector_type(4))) float f32x4;   // MFMA C/D frag

#define MFMA(a, b, c) __builtin_amdgcn_mfma_f32_16x16x32_bf16((a), (b), (c), 0, 0, 0)

__device__ __forceinline__ float sigmoidf(float x) {
    return 1.0f / (1.0f + expf(-x));
}

__device__ __forceinline__ unsigned short f2bf(float f) {   // RNE f32 -> bf16
    unsigned u = __float_as_uint(f);
    u += 0x7FFFu + ((u >> 16) & 1u);
    return (unsigned short)(u >> 16);
}

// Block j processes TWO sequences through the same MFMAs:
//   B-column parity 0 = sequence 0 (recomputed identically by every block),
//   B-column parity 1 = sequence j+1.
// Weights are staged global->LDS coalesced (XOR-swizzled), then read as
// fragments via ds_read_b128 — removes the 32-64 lines/instruction scatter
// of direct fragment loads (round-11 theory).
__global__ __launch_bounds__(TPB) void gru_fused(
    const int*   __restrict__ phr_inds,
    const int*   __restrict__ pos_inds,
    const int*   __restrict__ neg_inds,
    const float* __restrict__ u_emb,
    const float* __restrict__ v_emb,
    const float* __restrict__ w_ih,
    const float* __restrict__ w_hh,
    const float* __restrict__ b_ih,
    const float* __restrict__ b_hh,
    const float* __restrict__ h0,
    float*       __restrict__ slots,    // [NBLK*SLOT_STRIDE] workspace (s scalars)
    unsigned*    __restrict__ flags,    // [NBLK*FLAG_STRIDE] workspace
    float*       __restrict__ out)      // f32 scalar
{
    __shared__ __align__(16) unsigned short stage[SLAB_ROWS * E_SZ];  // 48 KB weight slab
    __shared__ __align__(16) unsigned short xs_bf16[2][16 * XS_STR];  // x^T per seq-group
    __shared__ __align__(16) float          gi_all[2][16 * GI_STR];   // gi[seq][col=l][row=g]
    __shared__ __align__(16) float          gh_s[2][3 * H_SZ];        // gh exchange per seq
    __shared__ __align__(16) unsigned short hs_bf16[2][H_SZ];         // h broadcast per seq
    __shared__ __align__(16) float          node[2][H_SZ];            // final h (f32) per seq

    const int bj   = blockIdx.x;             // 0..59
    const int seqB = bj + 1;                 // enc row this block owns (1..60)
    const int t    = threadIdx.x;
    const int lane = t & 63;
    const int wv   = t >> 6;                 // wave 0..5
    const int kg   = lane >> 4;              // k-group 0..3
    const int col  = lane & 15;              // B/D column for this lane
    const int arow = wv * 64 + col;          // A row (lane&15 = row within 16-block)

    // ---- gather x rows for BOTH sequences (deepest-latency loads first) ----
    for (int i = t; i < 2 * L_SZ * 32; i += TPB) {
        const int r  = i >> 5;               // 0..19
        const int e4 = i & 31;
        const int g  = (r < L_SZ) ? 0 : 1;
        const int l  = (r < L_SZ) ? r : r - L_SZ;
        int idx; const float* emb;
        if (g == 0)             { idx = phr_inds[l];                       emb = u_emb; }
        else if (seqB <= P_SZ)  { idx = pos_inds[(seqB - 1) * L_SZ + l];   emb = v_emb; }
        else                    { idx = neg_inds[(seqB - 1 - P_SZ) * L_SZ + l]; emb = v_emb; }
        const float4 v = *reinterpret_cast<const float4*>(emb + (size_t)idx * E_SZ + e4 * 4);
        short4 s4;
        s4.x = (short)f2bf(v.x); s4.y = (short)f2bf(v.y);
        s4.z = (short)f2bf(v.z); s4.w = (short)f2bf(v.w);
        *reinterpret_cast<short4*>((char*)&xs_bf16[g][0] + l * (XS_STR * 2) + e4 * 8) = s4;
    }
    // (cols 10..15 of each group left uninitialized: their gi outputs are never read)

    // ---- biases + h0 early (latency overlap; writes read only after barriers) ----
    const int gseq = t >> 7;                 // 0 or 1 (for t<256)
    const int gu   = t & 127;
    float bih_r = 0.f, bih_z = 0.f, bih_n = 0.f;
    float bhh_r = 0.f, bhh_z = 0.f, bhh_n = 0.f;
    float h_reg = 0.f;
    if (t < 2 * H_SZ) {
        bih_r = b_ih[gu]; bih_z = b_ih[gu + 128]; bih_n = b_ih[gu + 256];
        bhh_r = b_hh[gu]; bhh_z = b_hh[gu + 128]; bhh_n = b_hh[gu + 256];
        h_reg = h0[gu];
        hs_bf16[gseq][gu] = f2bf(h_reg);     // both groups init to h0
    }

    // ---- weights: coalesced global -> swizzled LDS slab -> register fragments ----
    bf16x8 aih[4][4], ahh[4][4];
    #pragma unroll
    for (int m = 0; m < 2; ++m) {
        const float* W = (m == 0) ? w_ih : w_hh;
        #pragma unroll
        for (int s = 0; s < 2; ++s) {
            // load 192 rows x 128 f32, fully coalesced (consecutive lanes -> consecutive 16B)
            #pragma unroll 8
            for (int q = 0; q < (SLAB_ROWS * E_SZ / 4) / TPB; ++q) {   // 16 iters
                const int fi = q * TPB + t;          // float4 index in slab
                const int lr = fi >> 5;              // local row 0..191
                const int e4 = fi & 31;
                const float4 v = *reinterpret_cast<const float4*>(
                    W + (size_t)(s * SLAB_ROWS + lr) * E_SZ + e4 * 4);
                short4 s4;
                s4.x = (short)f2bf(v.x); s4.y = (short)f2bf(v.y);
                s4.z = (short)f2bf(v.z); s4.w = (short)f2bf(v.w);
                const int byte = (lr * 256 + e4 * 8) ^ ((lr & 7) << 4);  // G4 XOR-swizzle
                *reinterpret_cast<short4*>((char*)stage + byte) = s4;
            }
            __syncthreads();                          // slab visible (also covers xs/hs writes)

            if (wv >= s * 3 && wv < (s + 1) * 3) {    // waves whose rows live in this slab
                const int lr0 = arow - s * SLAB_ROWS;
                #pragma unroll
                for (int mb = 0; mb < 4; ++mb) {
                    #pragma unroll
                    for (int kb = 0; kb < 4; ++kb) {
                        const int lr   = lr0 + mb * 16;
                        const int byte = (lr * 256 + kb * 64 + kg * 16) ^ ((lr & 7) << 4);
                        const bf16x8 f = *reinterpret_cast<const bf16x8*>((const char*)stage + byte);
                        if (m == 0) aih[mb][kb] = f;
                        else        ahh[mb][kb] = f;
                    }
                }
            }
            __syncthreads();                          // all reads done before slab overwrite
        }
    }
    // (last staging barrier also made xs_bf16 / hs_bf16 visible to everyone)

    // ---- gi = W_ih @ X^T, one MFMA pass per sequence group ----
    #pragma unroll
    for (int g = 0; g < 2; ++g) {
        f32x4 g0 = {0.f,0.f,0.f,0.f}, g1 = {0.f,0.f,0.f,0.f};
        f32x4 g2 = {0.f,0.f,0.f,0.f}, g3 = {0.f,0.f,0.f,0.f};
        #pragma unroll
        for (int kb = 0; kb < 4; ++kb) {
            const bf16x8 xb = *reinterpret_cast<const bf16x8*>(
                (const char*)&xs_bf16[g][0] + col * (XS_STR * 2) + kb * 64 + kg * 16);
            g0 = MFMA(aih[0][kb], xb, g0);
            g1 = MFMA(aih[1][kb], xb, g1);
            g2 = MFMA(aih[2][kb], xb, g2);
            g3 = MFMA(aih[3][kb], xb, g3);
        }
        const int rb = wv * 64 + kg * 4;     // D row base: (lane>>4)*4 + reg (m89-verified)
        *reinterpret_cast<f32x4*>(&gi_all[g][col * GI_STR + rb     ]) = g0;
        *reinterpret_cast<f32x4*>(&gi_all[g][col * GI_STR + rb + 16]) = g1;
        *reinterpret_cast<f32x4*>(&gi_all[g][col * GI_STR + rb + 32]) = g2;
        *reinterpret_cast<f32x4*>(&gi_all[g][col * GI_STR + rb + 48]) = g3;
    }
    // no barrier needed: step-0 barrier [A] orders gi_all writes before gate reads

    // ---- recurrent steps: 16 MFMA/wave/step, cols alternate seq0/seqB ----
    for (int l = 0; l < L_SZ; ++l) {
        f32x4 a0 = {0.f,0.f,0.f,0.f}, a1 = {0.f,0.f,0.f,0.f};
        f32x4 a2 = {0.f,0.f,0.f,0.f}, a3 = {0.f,0.f,0.f,0.f};
        #pragma unroll
        for (int kb = 0; kb < 4; ++kb) {
            // col parity selects which sequence's h this column multiplies
            const bf16x8 bh = *reinterpret_cast<const bf16x8*>(
                (const char*)&hs_bf16[col & 1][0] + kb * 64 + kg * 16);
            a0 = MFMA(ahh[0][kb], bh, a0);
            a1 = MFMA(ahh[1][kb], bh, a1);
            a2 = MFMA(ahh[2][kb], bh, a2);
            a3 = MFMA(ahh[3][kb], bh, a3);
        }
        if (col < 2) {                        // cols 0,1 hold gh for seq0 / seqB
            const int rb = wv * 64 + kg * 4;
            *reinterpret_cast<f32x4*>(&gh_s[col][rb     ]) = a0;
            *reinterpret_cast<f32x4*>(&gh_s[col][rb + 16]) = a1;
            *reinterpret_cast<f32x4*>(&gh_s[col][rb + 32]) = a2;
            *reinterpret_cast<f32x4*>(&gh_s[col][rb + 48]) = a3;
        }
        __syncthreads();                      // [A] gh_s (and, at l==0, gi_all) visible

        if (t < 2 * H_SZ) {
            const float* gi = &gi_all[gseq][l * GI_STR];
            const float* gh = &gh_s[gseq][0];
            const float r = sigmoidf(gi[gu      ] + bih_r + (gh[gu      ] + bhh_r));
            const float z = sigmoidf(gi[gu + 128] + bih_z + (gh[gu + 128] + bhh_z));
            const float n = tanhf  (gi[gu + 256] + bih_n + r * (gh[gu + 256] + bhh_n));
            h_reg = (1.0f - z) * n + z * h_reg;
            if (l < L_SZ - 1) hs_bf16[gseq][gu] = f2bf(h_reg);  // re-broadcast
            else              node[gseq][gu]   = h_reg;         // final h (f32)
        }
        __syncthreads();                      // [B] hs_bf16 / node visible
    }

    // ---- local dot: s = (node0 . node1) / 128, computed by wave 0 ----
    if (t >= 64) return;                      // no further barriers below

    float d = node[0][t] * node[1][t] + node[0][t + 64] * node[1][t + 64];
    #pragma unroll
    for (int off = 32; off > 0; off >>= 1) d += __shfl_down(d, off);
    const float s_own = d * (1.0f / (float)H_SZ);   // valid in lane 0

    // ---- publish (blocks 1..59) / aggregate (block 0) ----
    if (bj != 0) {
        if (t == 0) {
            slots[bj * SLOT_STRIDE] = s_own;   // plain store, bit-deterministic
            __threadfence();                   // release: slot visible before flag
            atomicExch(&flags[bj * FLAG_STRIDE], FLAG_MAGIC + (unsigned)bj);
        }
        return;
    }

    // block 0: lane k owns enc-row k+1. Lane 0 = own s; lanes 1..59 = block k's.
    float sv = 0.0f;
    if (t == 0) sv = s_own;
    else if (t < NSEQ) {
        const unsigned want = FLAG_MAGIC + (unsigned)t;
        while (atomicAdd(&flags[t * FLAG_STRIDE], 0u) != want) {
            __builtin_amdgcn_s_sleep(2);
        }
        __threadfence();                       // acquire: order slot read after flag
        sv = slots[t * SLOT_STRIDE];
    }

    float vp = 0.0f, vn = 0.0f;
    if (t < P_SZ)      vp = sv;                              // rows 1..10: pos
    else if (t < NSEQ) vn = (sv > 0.0f) ? expf(sv) : 0.0f;   // rows 11..60: neg

    #pragma unroll
    for (int off = 32; off > 0; off >>= 1) {
        vp += __shfl_down(vp, off);
        vn += __shfl_down(vn, off);
    }
    if (t == 0) {
        out[0] = logf(1.0f + vn) - vp;   // -(neg_loss + pos_loss)
    }
}

extern "C" void kernel_launch(void* const* d_in, const int* in_sizes, int n_in,
                              void* d_out, int out_size, void* d_ws, size_t ws_size,
                              hipStream_t stream) {
    const int*   phr_inds = (const int*)  d_in[0];
    const int*   pos_inds = (const int*)  d_in[1];
    const int*   neg_inds = (const int*)  d_in[2];
    const float* u_emb    = (const float*)d_in[3];
    const float* v_emb    = (const float*)d_in[4];
    const float* w_ih     = (const float*)d_in[5];
    const float* w_hh     = (const float*)d_in[6];
    const float* b_ih     = (const float*)d_in[7];
    const float* b_hh     = (const float*)d_in[8];
    const float* h0       = (const float*)d_in[9];

    float*    slots = (float*)d_ws;                       // s scalars (strided)
    unsigned* flags = (unsigned*)((char*)d_ws + 16384);   // separate region

    gru_fused<<<NBLK, TPB, 0, stream>>>(phr_inds, pos_inds, neg_inds,
                                        u_emb, v_emb, w_ih, w_hh, b_ih, b_hh, h0,
                                        slots, flags, (float*)d_out);
}